// Round 1
// 456.007 us; speedup vs baseline: 1.2258x; 1.2258x over previous
//
#include <hip/hip_runtime.h>
#include <hip/hip_bf16.h>

#define H 128
#define NSTEPS 8
#define DT_MAXF 0.125f
#define WAVES 4
#define PPW 16            // points per wave (one 16x16 MFMA N-tile)
#define PPB (WAVES*PPW)   // 64 points per block

typedef __attribute__((ext_vector_type(8))) short short8;   // 8 bf16 MFMA A/B frag
typedef __attribute__((ext_vector_type(4))) float floatx4;  // MFMA C/D frag

__device__ __forceinline__ float fast_tanh(float x) {
    float e = __builtin_amdgcn_exp2f(x * 2.8853900817779268f); // 2*log2(e)
    float r = __builtin_amdgcn_rcpf(e + 1.0f);
    return 1.0f - 2.0f * r;
}
__device__ __forceinline__ unsigned f2bf(float x) {           // fp32 -> bf16 bits, RNE (init-time)
    unsigned u = __float_as_uint(x);
    return (u + 0x7FFFu + ((u >> 16) & 1u)) >> 16;
}
__device__ __forceinline__ unsigned pk2(float a, float b) {   // packed bf16 cvt via union pun
    union { __hip_bfloat162 h; unsigned u; } U;
    U.h = __float22bfloat162_rn(make_float2(a, b));
    return U.u;
}
__device__ __forceinline__ short8 pack_bf8(const float* z) {
    union { unsigned u[4]; short8 s; } U;
    U.u[0] = pk2(z[0], z[1]); U.u[1] = pk2(z[2], z[3]);
    U.u[2] = pk2(z[4], z[5]); U.u[3] = pk2(z[6], z[7]);
    return U.s;
}

// Transposed MFMA orientation (A = W2^T, B = per-point frags; C/D col = own
// point). r9 proved the math; r9's 8 GB scratch FETCH came from unconstrained
// scheduling across the fully-unrolled MFMA nest (no phase fences -> Bf loads
// hoisted, live ranges exploded).
//
// R10 change: frags are now built ONCE per eval and reused across both tg
// groups (was: rebuilt per tg -> ~30% of VALU slots were redundant layer-1
// recompute incl. half the fast_tanh's). Register cost: +16 VGPR (eval A),
// +64 VGPR (eval B frags f0..f3[4]) -- affordable because LDS (68KB -> 2
// blocks/CU) is the occupancy binder, so the VGPR budget extends to 256 at
// no occupancy cost. Containment retained:
//   (1) sched_barrier(0) after the frag-build phase (keeps Bf loads out)
//   (2) sched_barrier(0) after every s-slice in the MFMA nest (max 4 Bf
//       loads hoisted at a time) and after each tg epilogue
// Math is bitwise identical to the previous version (same MFMA order/operands).
__global__ __launch_bounds__(256, 2)
void velwarp(const float* __restrict__ code, const float* __restrict__ pos,
             const float* __restrict__ t1g, const float* __restrict__ t2g,
             const float* __restrict__ W1, const float* __restrict__ b1,
             const float* __restrict__ W2, const float* __restrict__ b2,
             const float* __restrict__ W3, const float* __restrict__ b3,
             float* __restrict__ out, int N)
{
    __shared__ __align__(16) unsigned Wbuf[H*H/2];      // 32KB: W1 fp32 (init) then W2 bf16 frag-linear
    __shared__ __align__(16) float baseS[WAVES*8*64*4]; // 32KB: per-lane base1 (self-owned slots)
    __shared__ __align__(16) float W1xc[4][H];          // W1xc[c][u] = W1[64+c][u]
    __shared__ __align__(16) float4 W3s4[H];            // (W3[u][0..2], b2[u])

    const int tid = threadIdx.x;
    const int w   = tid >> 6;
    const int L   = tid & 63;
    const int m   = L & 15;      // this lane's point (C/D col); also z1-prep row
    const int q   = L >> 4;      // k-quad in frags; C/D row group = q*4+reg
    const int pb  = blockIdx.x * PPB + w * PPW;
    const int p   = pb + m;      // global point index (replicated over 4 q-lanes)

    // ---- stage W1 rows [0:64) as fp32 into Wbuf; small tables
    {
        const float4* s4 = (const float4*)W1;
        float4* d4 = (float4*)Wbuf;
        #pragma unroll 4
        for (int i = tid; i < (64*H)/4; i += 256) d4[i] = s4[i];
    }
    for (int idx = tid; idx < 4*H; idx += 256) {
        int c = idx >> 7, u = idx & (H-1);
        W1xc[c][u] = W1[(64 + c)*H + u];
    }
    for (int idx = tid; idx < H; idx += 256)
        W3s4[idx] = make_float4(W3[idx*3+0], W3[idx*3+1], W3[idx*3+2], b2[idx]);
    __syncthreads();

    // ---- base1[s][j] = b1[u] + code[point m] . W1[:64, u],  u = s*32 + q*8 + j
    {
        float base1[4][8];
        #pragma unroll
        for (int s = 0; s < 4; ++s) {
            float4 ba = *(const float4*)&b1[s*32 + q*8];
            float4 bb = *(const float4*)&b1[s*32 + q*8 + 4];
            base1[s][0]=ba.x; base1[s][1]=ba.y; base1[s][2]=ba.z; base1[s][3]=ba.w;
            base1[s][4]=bb.x; base1[s][5]=bb.y; base1[s][6]=bb.z; base1[s][7]=bb.w;
        }
        const float* Ws = (const float*)Wbuf;
        const float* crow = code + (size_t)p * 64;
        for (int i = 0; i < 64; ++i) {
            float c = crow[i];
            #pragma unroll
            for (int s = 0; s < 4; ++s) {
                const float* wrp = &Ws[i*H + s*32 + q*8];
                float4 wa = *(const float4*)wrp;
                float4 wb = *(const float4*)(wrp + 4);
                base1[s][0] = fmaf(c, wa.x, base1[s][0]);
                base1[s][1] = fmaf(c, wa.y, base1[s][1]);
                base1[s][2] = fmaf(c, wa.z, base1[s][2]);
                base1[s][3] = fmaf(c, wa.w, base1[s][3]);
                base1[s][4] = fmaf(c, wb.x, base1[s][4]);
                base1[s][5] = fmaf(c, wb.y, base1[s][5]);
                base1[s][6] = fmaf(c, wb.z, base1[s][6]);
                base1[s][7] = fmaf(c, wb.w, base1[s][7]);
            }
        }
        float4* b4 = (float4*)baseS;
        #pragma unroll
        for (int s = 0; s < 4; ++s) {
            b4[(w*8 + s*2 + 0)*64 + L] = make_float4(base1[s][0], base1[s][1], base1[s][2], base1[s][3]);
            b4[(w*8 + s*2 + 1)*64 + L] = make_float4(base1[s][4], base1[s][5], base1[s][6], base1[s][7]);
        }
    }
    __syncthreads();

    // ---- pack W2 -> bf16 fragment-linear == A-frag layout for A = W2^T
    for (int ch = tid; ch < 2048; ch += 256) {
        int ln = ch & 63, ts = ch >> 6;
        int s = ts & 3, t = ts >> 2;
        int k0 = s*32 + (ln >> 4)*8, n = t*16 + (ln & 15);
        unsigned pk0 = f2bf(W2[(k0+0)*H + n]) | (f2bf(W2[(k0+1)*H + n]) << 16);
        unsigned pk1 = f2bf(W2[(k0+2)*H + n]) | (f2bf(W2[(k0+3)*H + n]) << 16);
        unsigned pk2_ = f2bf(W2[(k0+4)*H + n]) | (f2bf(W2[(k0+5)*H + n]) << 16);
        unsigned pk3 = f2bf(W2[(k0+6)*H + n]) | (f2bf(W2[(k0+7)*H + n]) << 16);
        ((uint4*)Wbuf)[ch] = make_uint4(pk0, pk1, pk2_, pk3);
    }

    // ---- per-lane point state (replicated over the 4 q-lanes of point m)
    float px_ = pos[p*3+0], py_ = pos[p*3+1], pz_ = pos[p*3+2];
    float tc_ = t1g[p];
    float off_ = tc_ - t2g[p];
    float D[9];
    #pragma unroll
    for (int j = 0; j < 9; ++j) D[j] = (j==0||j==4||j==8) ? 1.0f : 0.0f;
    const float b30 = b3[0], b31 = b3[1], b32 = b3[2];
    __syncthreads();

    const short8* Bf = (const short8*)Wbuf;
    const float4* base4 = (const float4*)baseS;

    for (int step = 0; step < NSTEPS; ++step) {
        // ======== eval A: v(x,t) ========
        float vAx = 0.f, vAy = 0.f, vAz = 0.f;
        {
            float4 xt = make_float4(px_, py_, pz_, tc_);
            // -- build frags once (was: rebuilt per tg)
            short8 fA[4];
            #pragma unroll
            for (int s = 0; s < 4; ++s) {
                const int u0 = s*32 + q*8;
                float h[8];
                #pragma unroll
                for (int jh = 0; jh < 8; jh += 4) {
                    float4 bb = base4[(w*8 + s*2 + (jh >> 2))*64 + L];
                    float4 wx = *(const float4*)&W1xc[0][u0+jh];
                    float4 wy = *(const float4*)&W1xc[1][u0+jh];
                    float4 wz = *(const float4*)&W1xc[2][u0+jh];
                    float4 wt = *(const float4*)&W1xc[3][u0+jh];
                    h[jh+0] = fast_tanh(fmaf(xt.w,wt.x, fmaf(xt.z,wz.x, fmaf(xt.y,wy.x, fmaf(xt.x,wx.x, bb.x)))));
                    h[jh+1] = fast_tanh(fmaf(xt.w,wt.y, fmaf(xt.z,wz.y, fmaf(xt.y,wy.y, fmaf(xt.x,wx.y, bb.y)))));
                    h[jh+2] = fast_tanh(fmaf(xt.w,wt.z, fmaf(xt.z,wz.z, fmaf(xt.y,wy.z, fmaf(xt.x,wx.z, bb.z)))));
                    h[jh+3] = fast_tanh(fmaf(xt.w,wt.w, fmaf(xt.z,wz.w, fmaf(xt.y,wy.w, fmaf(xt.x,wx.w, bb.w)))));
                }
                fA[s] = pack_bf8(h);
            }
            __builtin_amdgcn_sched_barrier(0);
            // -- two tg MFMA passes from stored frags
            #pragma unroll
            for (int tg = 0; tg < 2; ++tg) {
                floatx4 accA[4];
                #pragma unroll
                for (int tt = 0; tt < 4; ++tt) accA[tt] = (floatx4){0.f,0.f,0.f,0.f};
                #pragma unroll
                for (int s = 0; s < 4; ++s) {
                    #pragma unroll
                    for (int tt = 0; tt < 4; ++tt)
                        accA[tt] = __builtin_amdgcn_mfma_f32_16x16x32_bf16(Bf[((tg*4+tt)*4+s)*64 + L], fA[s], accA[tt], 0, 0, 0);
                    __builtin_amdgcn_sched_barrier(0);
                }
                #pragma unroll
                for (int tt = 0; tt < 4; ++tt) {
                    const int t = tg*4 + tt;
                    #pragma unroll
                    for (int reg = 0; reg < 4; ++reg) {
                        float4 w3q = W3s4[t*16 + q*4 + reg];  // broadcast over 16 lanes
                        float h2 = fast_tanh(accA[tt][reg] + w3q.w);
                        vAx = fmaf(h2, w3q.x, vAx);
                        vAy = fmaf(h2, w3q.y, vAy);
                        vAz = fmaf(h2, w3q.z, vAz);
                    }
                }
                __builtin_amdgcn_sched_barrier(0);
            }
        }
        vAx += __shfl_xor(vAx, 16, 64); vAx += __shfl_xor(vAx, 32, 64);
        vAy += __shfl_xor(vAy, 16, 64); vAy += __shfl_xor(vAy, 32, 64);
        vAz += __shfl_xor(vAz, 16, 64); vAz += __shfl_xor(vAz, 32, 64);

        float dt_ = copysignf(fminf(fabsf(off_), DT_MAXF), off_);
        float hd = 0.5f * dt_;
        float mx = px_ - hd*(vAx + b30);
        float my = py_ - hd*(vAy + b31);
        float mz = pz_ - hd*(vAz + b32);
        float tm = tc_ - hd;

        // ======== eval B: v + Jacobian at midpoint ========
        float vx = 0.f, vy = 0.f, vz = 0.f;
        float Jr[9];
        #pragma unroll
        for (int oi = 0; oi < 9; ++oi) Jr[oi] = 0.f;
        {
            float4 xt = make_float4(mx, my, mz, tm);
            // -- build all 4 frag chains once (was: rebuilt per tg)
            short8 f0[4], f1[4], f2[4], f3[4];
            #pragma unroll
            for (int s = 0; s < 4; ++s) {
                const int u0 = s*32 + q*8;
                float h[8], d0[8], d1[8], d2[8];
                #pragma unroll
                for (int jh = 0; jh < 8; jh += 4) {
                    float4 bb = base4[(w*8 + s*2 + (jh >> 2))*64 + L];
                    float4 wx = *(const float4*)&W1xc[0][u0+jh];
                    float4 wy = *(const float4*)&W1xc[1][u0+jh];
                    float4 wz = *(const float4*)&W1xc[2][u0+jh];
                    float4 wt = *(const float4*)&W1xc[3][u0+jh];
                    #pragma unroll
                    for (int c4 = 0; c4 < 4; ++c4) {
                        float bbv = (c4==0)?bb.x:(c4==1)?bb.y:(c4==2)?bb.z:bb.w;
                        float wxv = (c4==0)?wx.x:(c4==1)?wx.y:(c4==2)?wx.z:wx.w;
                        float wyv = (c4==0)?wy.x:(c4==1)?wy.y:(c4==2)?wy.z:wy.w;
                        float wzv = (c4==0)?wz.x:(c4==1)?wz.y:(c4==2)?wz.z:wz.w;
                        float wtv = (c4==0)?wt.x:(c4==1)?wt.y:(c4==2)?wt.z:wt.w;
                        int j = jh + c4;
                        float zz = fmaf(xt.w,wtv, fmaf(xt.z,wzv, fmaf(xt.y,wyv, fmaf(xt.x,wxv, bbv))));
                        float hh = fast_tanh(zz);
                        float sd = fmaf(-hh, hh, 1.0f);
                        h[j]  = hh;
                        d0[j] = sd * wxv;
                        d1[j] = sd * wyv;
                        d2[j] = sd * wzv;
                    }
                }
                f0[s] = pack_bf8(h);
                f1[s] = pack_bf8(d0);
                f2[s] = pack_bf8(d1);
                f3[s] = pack_bf8(d2);
            }
            __builtin_amdgcn_sched_barrier(0);
            // -- two tg MFMA passes from stored frags
            #pragma unroll
            for (int tg = 0; tg < 2; ++tg) {
                floatx4 aB0[4], aB1[4], aB2[4], aB3[4];
                #pragma unroll
                for (int tt = 0; tt < 4; ++tt) {
                    aB0[tt] = (floatx4){0.f,0.f,0.f,0.f};
                    aB1[tt] = (floatx4){0.f,0.f,0.f,0.f};
                    aB2[tt] = (floatx4){0.f,0.f,0.f,0.f};
                    aB3[tt] = (floatx4){0.f,0.f,0.f,0.f};
                }
                #pragma unroll
                for (int s = 0; s < 4; ++s) {
                    #pragma unroll
                    for (int tt = 0; tt < 4; ++tt) {
                        short8 a = Bf[((tg*4+tt)*4+s)*64 + L];
                        aB0[tt] = __builtin_amdgcn_mfma_f32_16x16x32_bf16(a, f0[s], aB0[tt], 0, 0, 0);
                        aB1[tt] = __builtin_amdgcn_mfma_f32_16x16x32_bf16(a, f1[s], aB1[tt], 0, 0, 0);
                        aB2[tt] = __builtin_amdgcn_mfma_f32_16x16x32_bf16(a, f2[s], aB2[tt], 0, 0, 0);
                        aB3[tt] = __builtin_amdgcn_mfma_f32_16x16x32_bf16(a, f3[s], aB3[tt], 0, 0, 0);
                    }
                    __builtin_amdgcn_sched_barrier(0);
                }
                #pragma unroll
                for (int tt = 0; tt < 4; ++tt) {
                    const int t = tg*4 + tt;
                    #pragma unroll
                    for (int reg = 0; reg < 4; ++reg) {
                        float4 w3q = W3s4[t*16 + q*4 + reg];
                        float h2 = fast_tanh(aB0[tt][reg] + w3q.w);
                        float s2 = fmaf(-h2, h2, 1.0f);
                        vx = fmaf(h2, w3q.x, vx);
                        vy = fmaf(h2, w3q.y, vy);
                        vz = fmaf(h2, w3q.z, vz);
                        float dd0 = s2*aB1[tt][reg], dd1 = s2*aB2[tt][reg], dd2 = s2*aB3[tt][reg];
                        Jr[0] = fmaf(dd0, w3q.x, Jr[0]);
                        Jr[1] = fmaf(dd1, w3q.x, Jr[1]);
                        Jr[2] = fmaf(dd2, w3q.x, Jr[2]);
                        Jr[3] = fmaf(dd0, w3q.y, Jr[3]);
                        Jr[4] = fmaf(dd1, w3q.y, Jr[4]);
                        Jr[5] = fmaf(dd2, w3q.y, Jr[5]);
                        Jr[6] = fmaf(dd0, w3q.z, Jr[6]);
                        Jr[7] = fmaf(dd1, w3q.z, Jr[7]);
                        Jr[8] = fmaf(dd2, w3q.z, Jr[8]);
                    }
                }
                __builtin_amdgcn_sched_barrier(0);
            }
        }
        vx += __shfl_xor(vx, 16, 64); vx += __shfl_xor(vx, 32, 64);
        vy += __shfl_xor(vy, 16, 64); vy += __shfl_xor(vy, 32, 64);
        vz += __shfl_xor(vz, 16, 64); vz += __shfl_xor(vz, 32, 64);
        #pragma unroll
        for (int oi = 0; oi < 9; ++oi) {
            Jr[oi] += __shfl_xor(Jr[oi], 16, 64);
            Jr[oi] += __shfl_xor(Jr[oi], 32, 64);
        }
        vx += b30; vy += b31; vz += b32;

        // def + state update, replicated identically in all 4 q-lanes
        float nd[9];
        #pragma unroll
        for (int o = 0; o < 3; ++o)
            #pragma unroll
            for (int c = 0; c < 3; ++c)
                nd[o*3+c] = D[o*3+c] - dt_*(Jr[o*3+0]*D[0*3+c] + Jr[o*3+1]*D[1*3+c] + Jr[o*3+2]*D[2*3+c]);
        #pragma unroll
        for (int j = 0; j < 9; ++j) D[j] = nd[j];
        px_ = fmaf(-dt_, vx, px_);
        py_ = fmaf(-dt_, vy, py_);
        pz_ = fmaf(-dt_, vz, pz_);
        tc_  -= dt_;
        off_ -= dt_;
    }

    // ---- output: q==0 lane of each point writes xyz + deform
    if (q == 0) {
        out[p*3+0] = px_; out[p*3+1] = py_; out[p*3+2] = pz_;
        float* o9 = out + (size_t)N*3 + (size_t)p*9;
        #pragma unroll
        for (int j = 0; j < 9; ++j) o9[j] = D[j];
    }
}

extern "C" void kernel_launch(void* const* d_in, const int* in_sizes, int n_in,
                              void* d_out, int out_size, void* d_ws, size_t ws_size,
                              hipStream_t stream) {
    const float* code = (const float*)d_in[0];
    const float* pos  = (const float*)d_in[1];
    const float* t1   = (const float*)d_in[2];
    const float* t2   = (const float*)d_in[3];
    const float* W1   = (const float*)d_in[4];
    const float* b1   = (const float*)d_in[5];
    const float* W2   = (const float*)d_in[6];
    const float* b2   = (const float*)d_in[7];
    const float* W3   = (const float*)d_in[8];
    const float* b3   = (const float*)d_in[9];
    float* out = (float*)d_out;
    const int N = in_sizes[1] / 3;           // 131072
    const int blocks = N / PPB;              // 2048
    velwarp<<<blocks, 256, 0, stream>>>(code, pos, t1, t2, W1, b1, W2, b2, W3, b3, out, N);
}

// Round 2
// 420.636 us; speedup vs baseline: 1.3289x; 1.0841x over previous
//
#include <hip/hip_runtime.h>
#include <hip/hip_bf16.h>

#define H 128
#define NSTEPS 8
#define DT_MAXF 0.125f
#define WAVES 4
#define PPW 16            // points per wave (one 16x16 MFMA N-tile)
#define PPB (WAVES*PPW)   // 64 points per block

typedef __attribute__((ext_vector_type(8))) short short8;   // 8 bf16 MFMA A/B frag
typedef __attribute__((ext_vector_type(4))) float floatx4;  // MFMA C/D frag
typedef __attribute__((ext_vector_type(2))) float f32x2;    // packed-FP32 pair (v_pk_*_f32)

__device__ __forceinline__ f32x2 sp2(float v) { return (f32x2){v, v}; }
__device__ __forceinline__ f32x2 fma2(f32x2 a, f32x2 b, f32x2 c) {
    return __builtin_elementwise_fma(a, b, c);              // -> v_pk_fma_f32
}
// identical math to old fast_tanh per half: e=exp2(x*2log2e); r=rcp(e+1); 1-2r
__device__ __forceinline__ f32x2 tanh2(f32x2 x) {
    f32x2 y = x * 2.8853900817779268f;
    f32x2 e; e[0] = __builtin_amdgcn_exp2f(y[0]); e[1] = __builtin_amdgcn_exp2f(y[1]);
    f32x2 ep = e + 1.0f;
    f32x2 r; r[0] = __builtin_amdgcn_rcpf(ep[0]); r[1] = __builtin_amdgcn_rcpf(ep[1]);
    return fma2(sp2(-2.0f), r, sp2(1.0f));
}
__device__ __forceinline__ float fast_tanh(float x) {
    float e = __builtin_amdgcn_exp2f(x * 2.8853900817779268f);
    float r = __builtin_amdgcn_rcpf(e + 1.0f);
    return 1.0f - 2.0f * r;
}
__device__ __forceinline__ unsigned f2bf(float x) {           // fp32 -> bf16 bits, RNE (init-time)
    unsigned u = __float_as_uint(x);
    return (u + 0x7FFFu + ((u >> 16) & 1u)) >> 16;
}
__device__ __forceinline__ unsigned pk2(float a, float b) {   // packed bf16 cvt
    union { __hip_bfloat162 h; unsigned u; } U;
    U.h = __float22bfloat162_rn(make_float2(a, b));
    return U.u;
}
__device__ __forceinline__ short8 pack_bf8v(const f32x2* z) { // 4 pairs -> 8 bf16
    union { unsigned u[4]; short8 s; } U;
    U.u[0] = pk2(z[0][0], z[0][1]); U.u[1] = pk2(z[1][0], z[1][1]);
    U.u[2] = pk2(z[2][0], z[2][1]); U.u[3] = pk2(z[3][0], z[3][1]);
    return U.s;
}

// Transposed MFMA orientation (A = W2^T, B = per-point frags; C/D col = own
// point). r9 proved the math; r10 added frag-build-once (+20%).
//
// R11 changes (issue-bound on VALU port: VALUBusy 68 + MfmaUtil 17 = 85%):
//   (1) all scalar fp32 fma/mul chains rewritten over f32x2 -> v_pk_fma_f32
//       (VOP3P dual-FP32, gfx90a+): layer-1 z, tanh non-trans ops, sd/d-muls,
//       layer-3 epilogue. Halves their issue-slot cost. Per-chain bitwise
//       identical; only v/Jr accumulator fold order reassociates (1-ulp).
//   (2) base1 kept in 32 VGPRs instead of the baseS LDS round-trip (the slots
//       were purely self-owned: writer lane == reader lane). -32KB LDS,
//       -16 ds_read_b128/lane/step. VGPR headroom: 128 used of 256 budget.
//   (3) W3/b2 re-laid as pair-wise float4s (W3pA={x0,x1,y0,y1},
//       W3pB={z0,z1,b2_0,b2_1}) so the packed epilogue keeps b128 loads.
// Containment retained: sched_barrier(0) after frag build, after each s-slice
// MFMA group, after each tg epilogue.
__global__ __launch_bounds__(256, 2)
void velwarp(const float* __restrict__ code, const float* __restrict__ pos,
             const float* __restrict__ t1g, const float* __restrict__ t2g,
             const float* __restrict__ W1, const float* __restrict__ b1,
             const float* __restrict__ W2, const float* __restrict__ b2,
             const float* __restrict__ W3, const float* __restrict__ b3,
             float* __restrict__ out, int N)
{
    __shared__ __align__(16) unsigned Wbuf[H*H/2];      // 32KB: W1 fp32 (init) then W2 bf16 frag-linear
    __shared__ __align__(16) float W1xc[4][H];          // W1xc[c][u] = W1[64+c][u]
    __shared__ __align__(16) floatx4 W3pA[H/2];         // pair u0=2i: {W3x[u0],W3x[u0+1],W3y[u0],W3y[u0+1]}
    __shared__ __align__(16) floatx4 W3pB[H/2];         // pair u0=2i: {W3z[u0],W3z[u0+1],b2[u0],b2[u0+1]}

    const int tid = threadIdx.x;
    const int w   = tid >> 6;  (void)w;
    const int L   = tid & 63;
    const int m   = L & 15;      // this lane's point (C/D col)
    const int q   = L >> 4;      // k-quad in frags; C/D row group = q*4+reg
    const int pb  = blockIdx.x * PPB + (tid >> 6) * PPW;
    const int p   = pb + m;      // global point index (replicated over 4 q-lanes)

    // ---- stage W1 rows [0:64) as fp32 into Wbuf; small tables
    {
        const float4* s4 = (const float4*)W1;
        float4* d4 = (float4*)Wbuf;
        #pragma unroll 4
        for (int i = tid; i < (64*H)/4; i += 256) d4[i] = s4[i];
    }
    for (int idx = tid; idx < 4*H; idx += 256) {
        int c = idx >> 7, u = idx & (H-1);
        W1xc[c][u] = W1[(64 + c)*H + u];
    }
    if (tid < H/2) {
        int u0 = tid*2;
        W3pA[tid] = (floatx4){W3[u0*3+0], W3[(u0+1)*3+0], W3[u0*3+1], W3[(u0+1)*3+1]};
        W3pB[tid] = (floatx4){W3[u0*3+2], W3[(u0+1)*3+2], b2[u0], b2[u0+1]};
    }
    __syncthreads();

    // ---- base1[s][pair] = b1[u] + code[point p] . W1[:64, u],  u = s*32 + q*8 + 2*pair
    f32x2 base1[4][4];
    {
        #pragma unroll
        for (int s = 0; s < 4; ++s) {
            floatx4 ba = *(const floatx4*)&b1[s*32 + q*8];
            floatx4 bb = *(const floatx4*)&b1[s*32 + q*8 + 4];
            base1[s][0] = ba.xy; base1[s][1] = ba.zw;
            base1[s][2] = bb.xy; base1[s][3] = bb.zw;
        }
        const float* Ws = (const float*)Wbuf;
        const float* crow = code + (size_t)p * 64;
        for (int i = 0; i < 64; ++i) {
            f32x2 c = sp2(crow[i]);
            #pragma unroll
            for (int s = 0; s < 4; ++s) {
                const float* wrp = &Ws[i*H + s*32 + q*8];
                floatx4 wa = *(const floatx4*)wrp;
                floatx4 wb = *(const floatx4*)(wrp + 4);
                base1[s][0] = fma2(c, wa.xy, base1[s][0]);
                base1[s][1] = fma2(c, wa.zw, base1[s][1]);
                base1[s][2] = fma2(c, wb.xy, base1[s][2]);
                base1[s][3] = fma2(c, wb.zw, base1[s][3]);
            }
        }
    }
    __syncthreads();   // all lanes done reading W1 from Wbuf before repack

    // ---- pack W2 -> bf16 fragment-linear == A-frag layout for A = W2^T
    for (int ch = tid; ch < 2048; ch += 256) {
        int ln = ch & 63, ts = ch >> 6;
        int s = ts & 3, t = ts >> 2;
        int k0 = s*32 + (ln >> 4)*8, n = t*16 + (ln & 15);
        unsigned pk0 = f2bf(W2[(k0+0)*H + n]) | (f2bf(W2[(k0+1)*H + n]) << 16);
        unsigned pk1 = f2bf(W2[(k0+2)*H + n]) | (f2bf(W2[(k0+3)*H + n]) << 16);
        unsigned pk2_ = f2bf(W2[(k0+4)*H + n]) | (f2bf(W2[(k0+5)*H + n]) << 16);
        unsigned pk3 = f2bf(W2[(k0+6)*H + n]) | (f2bf(W2[(k0+7)*H + n]) << 16);
        ((uint4*)Wbuf)[ch] = make_uint4(pk0, pk1, pk2_, pk3);
    }

    // ---- per-lane point state (replicated over the 4 q-lanes of point m)
    float px_ = pos[p*3+0], py_ = pos[p*3+1], pz_ = pos[p*3+2];
    float tc_ = t1g[p];
    float off_ = tc_ - t2g[p];
    float D[9];
    #pragma unroll
    for (int j = 0; j < 9; ++j) D[j] = (j==0||j==4||j==8) ? 1.0f : 0.0f;
    const float b30 = b3[0], b31 = b3[1], b32 = b3[2];
    __syncthreads();

    const short8* Bf = (const short8*)Wbuf;

    for (int step = 0; step < NSTEPS; ++step) {
        // ======== eval A: v(x,t) ========
        f32x2 vAx2 = sp2(0.f), vAy2 = sp2(0.f), vAz2 = sp2(0.f);
        {
            float4 xt = make_float4(px_, py_, pz_, tc_);
            f32x2 sx = sp2(xt.x), sy = sp2(xt.y), sz = sp2(xt.z), st = sp2(xt.w);
            // -- build frags once
            short8 fA[4];
            #pragma unroll
            for (int s = 0; s < 4; ++s) {
                const int u0 = s*32 + q*8;
                f32x2 hv[4];
                #pragma unroll
                for (int jh = 0; jh < 8; jh += 4) {
                    const int pb0 = jh >> 1;
                    floatx4 wx = *(const floatx4*)&W1xc[0][u0+jh];
                    floatx4 wy = *(const floatx4*)&W1xc[1][u0+jh];
                    floatx4 wz = *(const floatx4*)&W1xc[2][u0+jh];
                    floatx4 wt = *(const floatx4*)&W1xc[3][u0+jh];
                    f32x2 z0 = fma2(st, wt.xy, fma2(sz, wz.xy, fma2(sy, wy.xy, fma2(sx, wx.xy, base1[s][pb0]))));
                    f32x2 z1 = fma2(st, wt.zw, fma2(sz, wz.zw, fma2(sy, wy.zw, fma2(sx, wx.zw, base1[s][pb0+1]))));
                    hv[pb0]   = tanh2(z0);
                    hv[pb0+1] = tanh2(z1);
                }
                fA[s] = pack_bf8v(hv);
            }
            __builtin_amdgcn_sched_barrier(0);
            // -- two tg MFMA passes from stored frags
            #pragma unroll
            for (int tg = 0; tg < 2; ++tg) {
                floatx4 accA[4];
                #pragma unroll
                for (int tt = 0; tt < 4; ++tt) accA[tt] = (floatx4){0.f,0.f,0.f,0.f};
                #pragma unroll
                for (int s = 0; s < 4; ++s) {
                    #pragma unroll
                    for (int tt = 0; tt < 4; ++tt)
                        accA[tt] = __builtin_amdgcn_mfma_f32_16x16x32_bf16(Bf[((tg*4+tt)*4+s)*64 + L], fA[s], accA[tt], 0, 0, 0);
                    __builtin_amdgcn_sched_barrier(0);
                }
                #pragma unroll
                for (int tt = 0; tt < 4; ++tt) {
                    const int t = tg*4 + tt;
                    const int pu = t*8 + q*2;
                    floatx4 pa0 = W3pA[pu],   pB0 = W3pB[pu];     // regs 0,1
                    floatx4 pa1 = W3pA[pu+1], pB1 = W3pB[pu+1];   // regs 2,3
                    f32x2 h0 = tanh2(accA[tt].xy + pB0.zw);
                    vAx2 = fma2(h0, pa0.xy, vAx2);
                    vAy2 = fma2(h0, pa0.zw, vAy2);
                    vAz2 = fma2(h0, pB0.xy, vAz2);
                    f32x2 h1 = tanh2(accA[tt].zw + pB1.zw);
                    vAx2 = fma2(h1, pa1.xy, vAx2);
                    vAy2 = fma2(h1, pa1.zw, vAy2);
                    vAz2 = fma2(h1, pB1.xy, vAz2);
                }
                __builtin_amdgcn_sched_barrier(0);
            }
        }
        float vAx = vAx2[0] + vAx2[1];
        float vAy = vAy2[0] + vAy2[1];
        float vAz = vAz2[0] + vAz2[1];
        vAx += __shfl_xor(vAx, 16, 64); vAx += __shfl_xor(vAx, 32, 64);
        vAy += __shfl_xor(vAy, 16, 64); vAy += __shfl_xor(vAy, 32, 64);
        vAz += __shfl_xor(vAz, 16, 64); vAz += __shfl_xor(vAz, 32, 64);

        float dt_ = copysignf(fminf(fabsf(off_), DT_MAXF), off_);
        float hd = 0.5f * dt_;
        float mx = px_ - hd*(vAx + b30);
        float my = py_ - hd*(vAy + b31);
        float mz = pz_ - hd*(vAz + b32);
        float tm = tc_ - hd;

        // ======== eval B: v + Jacobian at midpoint ========
        f32x2 vx2 = sp2(0.f), vy2 = sp2(0.f), vz2 = sp2(0.f);
        f32x2 Jr2[9];
        #pragma unroll
        for (int oi = 0; oi < 9; ++oi) Jr2[oi] = sp2(0.f);
        {
            f32x2 sx = sp2(mx), sy = sp2(my), sz = sp2(mz), st = sp2(tm);
            // -- build all 4 frag chains once
            short8 f0[4], f1[4], f2[4], f3[4];
            #pragma unroll
            for (int s = 0; s < 4; ++s) {
                const int u0 = s*32 + q*8;
                f32x2 h[4], d0[4], d1[4], d2[4];
                #pragma unroll
                for (int jh = 0; jh < 8; jh += 4) {
                    const int pb0 = jh >> 1;
                    floatx4 wx = *(const floatx4*)&W1xc[0][u0+jh];
                    floatx4 wy = *(const floatx4*)&W1xc[1][u0+jh];
                    floatx4 wz = *(const floatx4*)&W1xc[2][u0+jh];
                    floatx4 wt = *(const floatx4*)&W1xc[3][u0+jh];
                    f32x2 z0 = fma2(st, wt.xy, fma2(sz, wz.xy, fma2(sy, wy.xy, fma2(sx, wx.xy, base1[s][pb0]))));
                    f32x2 z1 = fma2(st, wt.zw, fma2(sz, wz.zw, fma2(sy, wy.zw, fma2(sx, wx.zw, base1[s][pb0+1]))));
                    f32x2 hh0 = tanh2(z0);
                    f32x2 hh1 = tanh2(z1);
                    f32x2 sd0 = fma2(-hh0, hh0, sp2(1.0f));
                    f32x2 sd1 = fma2(-hh1, hh1, sp2(1.0f));
                    h[pb0] = hh0;            h[pb0+1] = hh1;
                    d0[pb0] = sd0 * wx.xy;   d0[pb0+1] = sd1 * wx.zw;
                    d1[pb0] = sd0 * wy.xy;   d1[pb0+1] = sd1 * wy.zw;
                    d2[pb0] = sd0 * wz.xy;   d2[pb0+1] = sd1 * wz.zw;
                }
                f0[s] = pack_bf8v(h);
                f1[s] = pack_bf8v(d0);
                f2[s] = pack_bf8v(d1);
                f3[s] = pack_bf8v(d2);
            }
            __builtin_amdgcn_sched_barrier(0);
            // -- two tg MFMA passes from stored frags
            #pragma unroll
            for (int tg = 0; tg < 2; ++tg) {
                floatx4 aB0[4], aB1[4], aB2[4], aB3[4];
                #pragma unroll
                for (int tt = 0; tt < 4; ++tt) {
                    aB0[tt] = (floatx4){0.f,0.f,0.f,0.f};
                    aB1[tt] = (floatx4){0.f,0.f,0.f,0.f};
                    aB2[tt] = (floatx4){0.f,0.f,0.f,0.f};
                    aB3[tt] = (floatx4){0.f,0.f,0.f,0.f};
                }
                #pragma unroll
                for (int s = 0; s < 4; ++s) {
                    #pragma unroll
                    for (int tt = 0; tt < 4; ++tt) {
                        short8 a = Bf[((tg*4+tt)*4+s)*64 + L];
                        aB0[tt] = __builtin_amdgcn_mfma_f32_16x16x32_bf16(a, f0[s], aB0[tt], 0, 0, 0);
                        aB1[tt] = __builtin_amdgcn_mfma_f32_16x16x32_bf16(a, f1[s], aB1[tt], 0, 0, 0);
                        aB2[tt] = __builtin_amdgcn_mfma_f32_16x16x32_bf16(a, f2[s], aB2[tt], 0, 0, 0);
                        aB3[tt] = __builtin_amdgcn_mfma_f32_16x16x32_bf16(a, f3[s], aB3[tt], 0, 0, 0);
                    }
                    __builtin_amdgcn_sched_barrier(0);
                }
                #pragma unroll
                for (int tt = 0; tt < 4; ++tt) {
                    const int t = tg*4 + tt;
                    const int pu = t*8 + q*2;
                    floatx4 pa0 = W3pA[pu],   pB0 = W3pB[pu];     // regs 0,1
                    floatx4 pa1 = W3pA[pu+1], pB1 = W3pB[pu+1];   // regs 2,3
                    // pair 0 (regs 0,1)
                    f32x2 h0 = tanh2(aB0[tt].xy + pB0.zw);
                    f32x2 s20 = fma2(-h0, h0, sp2(1.0f));
                    vx2 = fma2(h0, pa0.xy, vx2);
                    vy2 = fma2(h0, pa0.zw, vy2);
                    vz2 = fma2(h0, pB0.xy, vz2);
                    f32x2 dd0 = s20 * aB1[tt].xy, dd1 = s20 * aB2[tt].xy, dd2 = s20 * aB3[tt].xy;
                    Jr2[0] = fma2(dd0, pa0.xy, Jr2[0]);
                    Jr2[1] = fma2(dd1, pa0.xy, Jr2[1]);
                    Jr2[2] = fma2(dd2, pa0.xy, Jr2[2]);
                    Jr2[3] = fma2(dd0, pa0.zw, Jr2[3]);
                    Jr2[4] = fma2(dd1, pa0.zw, Jr2[4]);
                    Jr2[5] = fma2(dd2, pa0.zw, Jr2[5]);
                    Jr2[6] = fma2(dd0, pB0.xy, Jr2[6]);
                    Jr2[7] = fma2(dd1, pB0.xy, Jr2[7]);
                    Jr2[8] = fma2(dd2, pB0.xy, Jr2[8]);
                    // pair 1 (regs 2,3)
                    f32x2 h1 = tanh2(aB0[tt].zw + pB1.zw);
                    f32x2 s21 = fma2(-h1, h1, sp2(1.0f));
                    vx2 = fma2(h1, pa1.xy, vx2);
                    vy2 = fma2(h1, pa1.zw, vy2);
                    vz2 = fma2(h1, pB1.xy, vz2);
                    f32x2 ee0 = s21 * aB1[tt].zw, ee1 = s21 * aB2[tt].zw, ee2 = s21 * aB3[tt].zw;
                    Jr2[0] = fma2(ee0, pa1.xy, Jr2[0]);
                    Jr2[1] = fma2(ee1, pa1.xy, Jr2[1]);
                    Jr2[2] = fma2(ee2, pa1.xy, Jr2[2]);
                    Jr2[3] = fma2(ee0, pa1.zw, Jr2[3]);
                    Jr2[4] = fma2(ee1, pa1.zw, Jr2[4]);
                    Jr2[5] = fma2(ee2, pa1.zw, Jr2[5]);
                    Jr2[6] = fma2(ee0, pB1.xy, Jr2[6]);
                    Jr2[7] = fma2(ee1, pB1.xy, Jr2[7]);
                    Jr2[8] = fma2(ee2, pB1.xy, Jr2[8]);
                }
                __builtin_amdgcn_sched_barrier(0);
            }
        }
        float vx = vx2[0] + vx2[1];
        float vy = vy2[0] + vy2[1];
        float vz = vz2[0] + vz2[1];
        float Jr[9];
        #pragma unroll
        for (int oi = 0; oi < 9; ++oi) Jr[oi] = Jr2[oi][0] + Jr2[oi][1];
        vx += __shfl_xor(vx, 16, 64); vx += __shfl_xor(vx, 32, 64);
        vy += __shfl_xor(vy, 16, 64); vy += __shfl_xor(vy, 32, 64);
        vz += __shfl_xor(vz, 16, 64); vz += __shfl_xor(vz, 32, 64);
        #pragma unroll
        for (int oi = 0; oi < 9; ++oi) {
            Jr[oi] += __shfl_xor(Jr[oi], 16, 64);
            Jr[oi] += __shfl_xor(Jr[oi], 32, 64);
        }
        vx += b30; vy += b31; vz += b32;

        // def + state update, replicated identically in all 4 q-lanes
        float nd[9];
        #pragma unroll
        for (int o = 0; o < 3; ++o)
            #pragma unroll
            for (int c = 0; c < 3; ++c)
                nd[o*3+c] = D[o*3+c] - dt_*(Jr[o*3+0]*D[0*3+c] + Jr[o*3+1]*D[1*3+c] + Jr[o*3+2]*D[2*3+c]);
        #pragma unroll
        for (int j = 0; j < 9; ++j) D[j] = nd[j];
        px_ = fmaf(-dt_, vx, px_);
        py_ = fmaf(-dt_, vy, py_);
        pz_ = fmaf(-dt_, vz, pz_);
        tc_  -= dt_;
        off_ -= dt_;
    }

    // ---- output: q==0 lane of each point writes xyz + deform
    if (q == 0) {
        out[p*3+0] = px_; out[p*3+1] = py_; out[p*3+2] = pz_;
        float* o9 = out + (size_t)N*3 + (size_t)p*9;
        #pragma unroll
        for (int j = 0; j < 9; ++j) o9[j] = D[j];
    }
}

extern "C" void kernel_launch(void* const* d_in, const int* in_sizes, int n_in,
                              void* d_out, int out_size, void* d_ws, size_t ws_size,
                              hipStream_t stream) {
    const float* code = (const float*)d_in[0];
    const float* pos  = (const float*)d_in[1];
    const float* t1   = (const float*)d_in[2];
    const float* t2   = (const float*)d_in[3];
    const float* W1   = (const float*)d_in[4];
    const float* b1   = (const float*)d_in[5];
    const float* W2   = (const float*)d_in[6];
    const float* b2   = (const float*)d_in[7];
    const float* W3   = (const float*)d_in[8];
    const float* b3   = (const float*)d_in[9];
    float* out = (float*)d_out;
    const int N = in_sizes[1] / 3;           // 131072
    const int blocks = N / PPB;              // 2048
    velwarp<<<blocks, 256, 0, stream>>>(code, pos, t1, t2, W1, b1, W2, b2, W3, b3, out, N);
}

// Round 3
// 400.165 us; speedup vs baseline: 1.3969x; 1.0512x over previous
//
#include <hip/hip_runtime.h>
#include <hip/hip_bf16.h>

#define H 128
#define NSTEPS 8
#define DT_MAXF 0.125f
#define WAVES 4
#define PPW 16            // points per wave (one 16x16 MFMA N-tile)
#define PPB (WAVES*PPW)   // 64 points per block

typedef __attribute__((ext_vector_type(8))) short short8;   // 8 bf16 MFMA A/B frag
typedef __attribute__((ext_vector_type(4))) float floatx4;  // MFMA C/D frag
typedef __attribute__((ext_vector_type(2))) float f32x2;    // packed-FP32 pair (v_pk_*_f32)

__device__ __forceinline__ f32x2 sp2(float v) { return (f32x2){v, v}; }
__device__ __forceinline__ f32x2 fma2(f32x2 a, f32x2 b, f32x2 c) {
    return __builtin_elementwise_fma(a, b, c);              // -> v_pk_fma_f32
}
// identical math to scalar fast_tanh per half: e=exp2(x*2log2e); r=rcp(e+1); 1-2r
__device__ __forceinline__ f32x2 tanh2(f32x2 x) {
    f32x2 y = x * 2.8853900817779268f;
    f32x2 e; e[0] = __builtin_amdgcn_exp2f(y[0]); e[1] = __builtin_amdgcn_exp2f(y[1]);
    f32x2 ep = e + 1.0f;
    f32x2 r; r[0] = __builtin_amdgcn_rcpf(ep[0]); r[1] = __builtin_amdgcn_rcpf(ep[1]);
    return fma2(sp2(-2.0f), r, sp2(1.0f));
}
__device__ __forceinline__ unsigned f2bf(float x) {           // fp32 -> bf16 bits, RNE
    unsigned u = __float_as_uint(x);
    return (u + 0x7FFFu + ((u >> 16) & 1u)) >> 16;
}
__device__ __forceinline__ unsigned pk2(float a, float b) {   // packed bf16 cvt
    union { __hip_bfloat162 h; unsigned u; } U;
    U.h = __float22bfloat162_rn(make_float2(a, b));
    return U.u;
}
__device__ __forceinline__ unsigned pkv(f32x2 v) { return pk2(v[0], v[1]); }
__device__ __forceinline__ short8 mk8(unsigned a, unsigned b, unsigned c, unsigned d) {
    union { unsigned u[4]; short8 s; } U;
    U.u[0] = a; U.u[1] = b; U.u[2] = c; U.u[3] = d; return U.s;
}
// xyzt B-frag, hi/lo split bf16: k0..3 = hi (pairs A-hi), k4..7 = lo (pairs A-hi),
// k8..11 = hi again (pairs A-lo). Lane q=0 carries hi+lo, q=1 carries hi, q>=2 zero.
__device__ __forceinline__ short8 xyzt_frag(float x, float y, float z, float t, int q) {
    unsigned hx = f2bf(x), hy = f2bf(y), hz = f2bf(z), ht = f2bf(t);
    float lx = x - __uint_as_float(hx << 16);
    float ly = y - __uint_as_float(hy << 16);
    float lz = z - __uint_as_float(hz << 16);
    float lt = t - __uint_as_float(ht << 16);
    unsigned w0 = hx | (hy << 16), w1 = hz | (ht << 16);
    unsigned w2 = pk2(lx, ly),     w3 = pk2(lz, lt);
    union { unsigned u[4]; short8 s; } F;
    F.u[0] = (q < 2)  ? w0 : 0u;
    F.u[1] = (q < 2)  ? w1 : 0u;
    F.u[2] = (q == 0) ? w2 : 0u;
    F.u[3] = (q == 0) ? w3 : 0u;
    return F.s;
}

// R12: all three matmul-shaped contractions now ride the MFMA pipe.
// Key trick: the MFMA k-index is an arbitrary permutation pi as long as the
// A-frag (weights, packed at init) and B-frag (activations) agree. We pick
// pi(slice s, lane q, j) = 32s + (j<4 ? 4q+j : 16+4q+(j-4)) so that the
// units a lane owns in C/D layout (u = 16t+4q+reg, tiles 2s,2s+1) are exactly
// its own B-slots for slice s -> C/D output feeds the next MFMA with ZERO
// cross-lane traffic.
//   L1: z = W1xyzt^T @ xyzt + base1C. xyzt/W1x split hi/lo bf16 (3-term
//       product => fp32-exact to ~2^-18); base1C (fp32, C/D layout, code.W1
//       precomputed) is the C operand -- no adds, no movs.
//   L2: as before (A = W2^T frags, now pi-permuted); C-in of slice 0 = b2
//       quad (fp32, folds the bias add); jac chains take a persistent ZERO4
//       quad as C (D!=C allowed) -- kills ~160 accvgpr zero-writes/step.
//   L3: v and Jr[3x3] = W3^T @ {h2, dd0, dd1, dd2} as 4-chain MFMA; the
//       cross-q reduction happens inside the MFMA, so all shuffle-reduces
//       are gone; 15 ds_bpermute broadcasts return v/Jr to all lanes.
// Containment: sched_barrier(0) after each phase (r9 lesson).
__global__ __launch_bounds__(256, 2)
void velwarp(const float* __restrict__ code, const float* __restrict__ pos,
             const float* __restrict__ t1g, const float* __restrict__ t2g,
             const float* __restrict__ W1, const float* __restrict__ b1,
             const float* __restrict__ W2, const float* __restrict__ b2,
             const float* __restrict__ W3, const float* __restrict__ b3,
             float* __restrict__ out, int N)
{
    __shared__ __align__(16) uint4 WbufU[2048];   // 32KB: W1 fp32 staging (init) then W2 bf16 frags
    __shared__ __align__(16) uint4 W1AU[8*64];    // 8KB : layer-1 A-frags (xyzt rows, hi/lo split)
    __shared__ __align__(16) uint4 W3AU[4*64];    // 4KB : layer-3 A-frags (W3^T, pi-permuted)
    __shared__ __align__(16) floatx4 WdX4[32];    // W1[64][u] in C/D order (= row-linear)
    __shared__ __align__(16) floatx4 WdY4[32];    // W1[65][u]
    __shared__ __align__(16) floatx4 WdZ4[32];    // W1[66][u]
    __shared__ __align__(16) floatx4 b2C4[32];    // b2 in C/D order

    const int tid = threadIdx.x;
    const int L   = tid & 63;
    const int m   = L & 15;      // this lane's point (C/D col)
    const int q   = L >> 4;      // C/D row group = q*4+reg; B-frag k-quad
    const int pb  = blockIdx.x * PPB + (tid >> 6) * PPW;
    const int p   = pb + m;      // global point index

    // ---- stage W1 rows [0:64) as fp32 into Wbuf
    {
        const float4* s4 = (const float4*)W1;
        float4* d4 = (float4*)WbufU;
        #pragma unroll 4
        for (int i = tid; i < (64*H)/4; i += 256) d4[i] = s4[i];
    }
    // ---- layer-1 A-frags: tile t, lane l: row u = 16t+(l&15); hi/lo split
    for (int e = tid; e < 512; e += 256) {
        int t = e >> 6, l = e & 63;
        int u = t*16 + (l & 15), qq = l >> 4;
        unsigned hb[4], lb[4];
        #pragma unroll
        for (int c = 0; c < 4; ++c) {
            float wv = W1[(64 + c)*H + u];
            unsigned hh = f2bf(wv);
            float wl = wv - __uint_as_float(hh << 16);
            hb[c] = hh; lb[c] = f2bf(wl);
        }
        unsigned hi01 = hb[0] | (hb[1] << 16), hi23 = hb[2] | (hb[3] << 16);
        unsigned lo01 = lb[0] | (lb[1] << 16), lo23 = lb[2] | (lb[3] << 16);
        uint4 o;
        if (qq == 0)      o = make_uint4(hi01, hi23, hi01, hi23);
        else if (qq == 1) o = make_uint4(lo01, lo23, 0u, 0u);
        else              o = make_uint4(0u, 0u, 0u, 0u);
        W1AU[e] = o;
    }
    // ---- layer-3 A-frags: slice s, lane l: row a = l&15 (rows 3..15 zero)
    for (int e = tid; e < 256; e += 256) {
        int s = e >> 6, l = e & 63;
        int a = l & 15, qq = l >> 4;
        uint4 o = make_uint4(0u, 0u, 0u, 0u);
        if (a < 3) {
            int u0 = s*32 + qq*4, u1 = u0 + 16;
            o.x = f2bf(W3[(u0+0)*3+a]) | (f2bf(W3[(u0+1)*3+a]) << 16);
            o.y = f2bf(W3[(u0+2)*3+a]) | (f2bf(W3[(u0+3)*3+a]) << 16);
            o.z = f2bf(W3[(u1+0)*3+a]) | (f2bf(W3[(u1+1)*3+a]) << 16);
            o.w = f2bf(W3[(u1+2)*3+a]) | (f2bf(W3[(u1+3)*3+a]) << 16);
        }
        W3AU[e] = o;
    }
    if (tid < 32) {
        WdX4[tid] = ((const floatx4*)(W1 + (size_t)64*H))[tid];
        WdY4[tid] = ((const floatx4*)(W1 + (size_t)65*H))[tid];
        WdZ4[tid] = ((const floatx4*)(W1 + (size_t)66*H))[tid];
        b2C4[tid] = ((const floatx4*)b2)[tid];
    }
    __syncthreads();

    // ---- base1C[t] (fp32, C/D layout): u = 16t + 4q + reg
    floatx4 base1C[8];
    {
        #pragma unroll
        for (int t = 0; t < 8; ++t) base1C[t] = *(const floatx4*)&b1[t*16 + q*4];
        const float* Ws = (const float*)WbufU;
        const float* crow = code + (size_t)p * 64;
        for (int i = 0; i < 64; ++i) {
            f32x2 c = sp2(crow[i]);
            #pragma unroll
            for (int t = 0; t < 8; ++t) {
                floatx4 wq = *(const floatx4*)&Ws[i*H + t*16 + q*4];
                base1C[t].xy = fma2(c, wq.xy, base1C[t].xy);
                base1C[t].zw = fma2(c, wq.zw, base1C[t].zw);
            }
        }
    }
    __syncthreads();   // all lanes done reading W1 fp32 before repack

    // ---- pack W2 -> bf16 A-frags with pi-permuted k
    for (int ch = tid; ch < 2048; ch += 256) {
        int ln = ch & 63, ts = ch >> 6;
        int s = ts & 3, t = ts >> 2;
        int qq = ln >> 4, n = t*16 + (ln & 15);
        int u0 = s*32 + qq*4, u1 = u0 + 16;
        unsigned w0 = f2bf(W2[(u0+0)*H+n]) | (f2bf(W2[(u0+1)*H+n]) << 16);
        unsigned w1 = f2bf(W2[(u0+2)*H+n]) | (f2bf(W2[(u0+3)*H+n]) << 16);
        unsigned w2 = f2bf(W2[(u1+0)*H+n]) | (f2bf(W2[(u1+1)*H+n]) << 16);
        unsigned w3v = f2bf(W2[(u1+2)*H+n]) | (f2bf(W2[(u1+3)*H+n]) << 16);
        WbufU[ch] = make_uint4(w0, w1, w2, w3v);
    }

    // ---- per-lane point state (kept replicated via bpermute broadcasts)
    float px_ = pos[p*3+0], py_ = pos[p*3+1], pz_ = pos[p*3+2];
    float tc_ = t1g[p];
    float off_ = tc_ - t2g[p];
    float D[9];
    #pragma unroll
    for (int j = 0; j < 9; ++j) D[j] = (j==0||j==4||j==8) ? 1.0f : 0.0f;
    const float b30 = b3[0], b31 = b3[1], b32 = b3[2];
    __syncthreads();

    const short8* Bf   = (const short8*)WbufU;
    const short8* W1Af = (const short8*)W1AU;
    const short8* W3Af = (const short8*)W3AU;
    const floatx4 Z4 = {0.f, 0.f, 0.f, 0.f};

    for (int step = 0; step < NSTEPS; ++step) {
        // ======== eval A: v(x,t) ========
        float vAx, vAy, vAz;
        {
            short8 xf = xyzt_frag(px_, py_, pz_, tc_, q);
            floatx4 z[8];
            #pragma unroll
            for (int t = 0; t < 8; ++t)
                z[t] = __builtin_amdgcn_mfma_f32_16x16x32_bf16(W1Af[t*64 + L], xf, base1C[t], 0, 0, 0);
            __builtin_amdgcn_sched_barrier(0);
            short8 fh[4];
            #pragma unroll
            for (int s = 0; s < 4; ++s) {
                f32x2 a0 = tanh2(z[2*s].xy),   a1 = tanh2(z[2*s].zw);
                f32x2 c0 = tanh2(z[2*s+1].xy), c1 = tanh2(z[2*s+1].zw);
                fh[s] = mk8(pkv(a0), pkv(a1), pkv(c0), pkv(c1));
            }
            __builtin_amdgcn_sched_barrier(0);
            floatx4 vacc = Z4;
            #pragma unroll
            for (int tg = 0; tg < 2; ++tg) {
                floatx4 acc[4];
                #pragma unroll
                for (int tt = 0; tt < 4; ++tt)
                    acc[tt] = __builtin_amdgcn_mfma_f32_16x16x32_bf16(
                        Bf[((tg*4+tt)*4 + 0)*64 + L], fh[0], b2C4[(tg*4+tt)*4 + q], 0, 0, 0);
                __builtin_amdgcn_sched_barrier(0);
                #pragma unroll
                for (int s = 1; s < 4; ++s) {
                    #pragma unroll
                    for (int tt = 0; tt < 4; ++tt)
                        acc[tt] = __builtin_amdgcn_mfma_f32_16x16x32_bf16(
                            Bf[((tg*4+tt)*4 + s)*64 + L], fh[s], acc[tt], 0, 0, 0);
                    __builtin_amdgcn_sched_barrier(0);
                }
                f32x2 e00 = tanh2(acc[0].xy), e01 = tanh2(acc[0].zw);
                f32x2 e10 = tanh2(acc[1].xy), e11 = tanh2(acc[1].zw);
                f32x2 e20 = tanh2(acc[2].xy), e21 = tanh2(acc[2].zw);
                f32x2 e30 = tanh2(acc[3].xy), e31 = tanh2(acc[3].zw);
                short8 ef0 = mk8(pkv(e00), pkv(e01), pkv(e10), pkv(e11));
                short8 ef1 = mk8(pkv(e20), pkv(e21), pkv(e30), pkv(e31));
                vacc = __builtin_amdgcn_mfma_f32_16x16x32_bf16(W3Af[(2*tg)*64 + L],   ef0, vacc, 0, 0, 0);
                vacc = __builtin_amdgcn_mfma_f32_16x16x32_bf16(W3Af[(2*tg+1)*64 + L], ef1, vacc, 0, 0, 0);
                __builtin_amdgcn_sched_barrier(0);
            }
            vAx = __shfl(vacc[0], m, 64);
            vAy = __shfl(vacc[1], m, 64);
            vAz = __shfl(vacc[2], m, 64);
        }

        float dt_ = copysignf(fminf(fabsf(off_), DT_MAXF), off_);
        float hd = 0.5f * dt_;
        float mx = px_ - hd*(vAx + b30);
        float my = py_ - hd*(vAy + b31);
        float mz = pz_ - hd*(vAz + b32);
        float tm = tc_ - hd;

        // ======== eval B: v + Jacobian at midpoint ========
        float vx, vy, vz, Jr[9];
        {
            short8 xf = xyzt_frag(mx, my, mz, tm, q);
            floatx4 z[8];
            #pragma unroll
            for (int t = 0; t < 8; ++t)
                z[t] = __builtin_amdgcn_mfma_f32_16x16x32_bf16(W1Af[t*64 + L], xf, base1C[t], 0, 0, 0);
            __builtin_amdgcn_sched_barrier(0);
            short8 fh[4], fd0[4], fd1[4], fd2[4];
            #pragma unroll
            for (int s = 0; s < 4; ++s) {
                unsigned uh[4], u0[4], u1[4], u2[4];
                #pragma unroll
                for (int hf = 0; hf < 2; ++hf) {
                    int t = 2*s + hf;
                    f32x2 h0 = tanh2(z[t].xy), h1 = tanh2(z[t].zw);
                    f32x2 s0 = fma2(-h0, h0, sp2(1.0f));
                    f32x2 s1 = fma2(-h1, h1, sp2(1.0f));
                    floatx4 wx = WdX4[t*4 + q], wy = WdY4[t*4 + q], wz = WdZ4[t*4 + q];
                    uh[2*hf+0] = pkv(h0);         uh[2*hf+1] = pkv(h1);
                    u0[2*hf+0] = pkv(s0 * wx.xy); u0[2*hf+1] = pkv(s1 * wx.zw);
                    u1[2*hf+0] = pkv(s0 * wy.xy); u1[2*hf+1] = pkv(s1 * wy.zw);
                    u2[2*hf+0] = pkv(s0 * wz.xy); u2[2*hf+1] = pkv(s1 * wz.zw);
                }
                fh[s]  = mk8(uh[0], uh[1], uh[2], uh[3]);
                fd0[s] = mk8(u0[0], u0[1], u0[2], u0[3]);
                fd1[s] = mk8(u1[0], u1[1], u1[2], u1[3]);
                fd2[s] = mk8(u2[0], u2[1], u2[2], u2[3]);
            }
            __builtin_amdgcn_sched_barrier(0);
            floatx4 V = Z4, J0 = Z4, J1 = Z4, J2 = Z4;
            #pragma unroll
            for (int tg = 0; tg < 2; ++tg) {
                floatx4 a0[4], a1[4], a2[4], a3[4];
                #pragma unroll
                for (int tt = 0; tt < 4; ++tt) {
                    short8 A = Bf[((tg*4+tt)*4 + 0)*64 + L];
                    a0[tt] = __builtin_amdgcn_mfma_f32_16x16x32_bf16(A, fh[0],  b2C4[(tg*4+tt)*4 + q], 0, 0, 0);
                    a1[tt] = __builtin_amdgcn_mfma_f32_16x16x32_bf16(A, fd0[0], Z4, 0, 0, 0);
                    a2[tt] = __builtin_amdgcn_mfma_f32_16x16x32_bf16(A, fd1[0], Z4, 0, 0, 0);
                    a3[tt] = __builtin_amdgcn_mfma_f32_16x16x32_bf16(A, fd2[0], Z4, 0, 0, 0);
                }
                __builtin_amdgcn_sched_barrier(0);
                #pragma unroll
                for (int s = 1; s < 4; ++s) {
                    #pragma unroll
                    for (int tt = 0; tt < 4; ++tt) {
                        short8 A = Bf[((tg*4+tt)*4 + s)*64 + L];
                        a0[tt] = __builtin_amdgcn_mfma_f32_16x16x32_bf16(A, fh[s],  a0[tt], 0, 0, 0);
                        a1[tt] = __builtin_amdgcn_mfma_f32_16x16x32_bf16(A, fd0[s], a1[tt], 0, 0, 0);
                        a2[tt] = __builtin_amdgcn_mfma_f32_16x16x32_bf16(A, fd1[s], a2[tt], 0, 0, 0);
                        a3[tt] = __builtin_amdgcn_mfma_f32_16x16x32_bf16(A, fd2[s], a3[tt], 0, 0, 0);
                    }
                    __builtin_amdgcn_sched_barrier(0);
                }
                // post: h2/s2/dd in C/D layout -> pi-packed e-frags -> L3 MFMA
                unsigned uh[8], u0[8], u1[8], u2[8];
                #pragma unroll
                for (int tt = 0; tt < 4; ++tt) {
                    f32x2 h0 = tanh2(a0[tt].xy), h1 = tanh2(a0[tt].zw);
                    f32x2 s0 = fma2(-h0, h0, sp2(1.0f));
                    f32x2 s1 = fma2(-h1, h1, sp2(1.0f));
                    uh[2*tt+0] = pkv(h0);              uh[2*tt+1] = pkv(h1);
                    u0[2*tt+0] = pkv(s0 * a1[tt].xy);  u0[2*tt+1] = pkv(s1 * a1[tt].zw);
                    u1[2*tt+0] = pkv(s0 * a2[tt].xy);  u1[2*tt+1] = pkv(s1 * a2[tt].zw);
                    u2[2*tt+0] = pkv(s0 * a3[tt].xy);  u2[2*tt+1] = pkv(s1 * a3[tt].zw);
                }
                short8 eh0 = mk8(uh[0], uh[1], uh[2], uh[3]), eh1 = mk8(uh[4], uh[5], uh[6], uh[7]);
                short8 e00 = mk8(u0[0], u0[1], u0[2], u0[3]), e01 = mk8(u0[4], u0[5], u0[6], u0[7]);
                short8 e10 = mk8(u1[0], u1[1], u1[2], u1[3]), e11 = mk8(u1[4], u1[5], u1[6], u1[7]);
                short8 e20 = mk8(u2[0], u2[1], u2[2], u2[3]), e21 = mk8(u2[4], u2[5], u2[6], u2[7]);
                const short8 WA0 = W3Af[(2*tg)*64 + L], WA1 = W3Af[(2*tg+1)*64 + L];
                V  = __builtin_amdgcn_mfma_f32_16x16x32_bf16(WA0, eh0, V,  0, 0, 0);
                V  = __builtin_amdgcn_mfma_f32_16x16x32_bf16(WA1, eh1, V,  0, 0, 0);
                J0 = __builtin_amdgcn_mfma_f32_16x16x32_bf16(WA0, e00, J0, 0, 0, 0);
                J0 = __builtin_amdgcn_mfma_f32_16x16x32_bf16(WA1, e01, J0, 0, 0, 0);
                J1 = __builtin_amdgcn_mfma_f32_16x16x32_bf16(WA0, e10, J1, 0, 0, 0);
                J1 = __builtin_amdgcn_mfma_f32_16x16x32_bf16(WA1, e11, J1, 0, 0, 0);
                J2 = __builtin_amdgcn_mfma_f32_16x16x32_bf16(WA0, e20, J2, 0, 0, 0);
                J2 = __builtin_amdgcn_mfma_f32_16x16x32_bf16(WA1, e21, J2, 0, 0, 0);
                __builtin_amdgcn_sched_barrier(0);
            }
            vx = __shfl(V[0], m, 64) + b30;
            vy = __shfl(V[1], m, 64) + b31;
            vz = __shfl(V[2], m, 64) + b32;
            Jr[0] = __shfl(J0[0], m, 64); Jr[1] = __shfl(J1[0], m, 64); Jr[2] = __shfl(J2[0], m, 64);
            Jr[3] = __shfl(J0[1], m, 64); Jr[4] = __shfl(J1[1], m, 64); Jr[5] = __shfl(J2[1], m, 64);
            Jr[6] = __shfl(J0[2], m, 64); Jr[7] = __shfl(J1[2], m, 64); Jr[8] = __shfl(J2[2], m, 64);
        }

        // def + state update, replicated identically in all lanes (inputs broadcast)
        float nd[9];
        #pragma unroll
        for (int o = 0; o < 3; ++o)
            #pragma unroll
            for (int c = 0; c < 3; ++c)
                nd[o*3+c] = D[o*3+c] - dt_*(Jr[o*3+0]*D[0*3+c] + Jr[o*3+1]*D[1*3+c] + Jr[o*3+2]*D[2*3+c]);
        #pragma unroll
        for (int j = 0; j < 9; ++j) D[j] = nd[j];
        px_ = fmaf(-dt_, vx, px_);
        py_ = fmaf(-dt_, vy, py_);
        pz_ = fmaf(-dt_, vz, pz_);
        tc_  -= dt_;
        off_ -= dt_;
    }

    // ---- output: q==0 lane of each point writes xyz + deform
    if (q == 0) {
        out[p*3+0] = px_; out[p*3+1] = py_; out[p*3+2] = pz_;
        float* o9 = out + (size_t)N*3 + (size_t)p*9;
        #pragma unroll
        for (int j = 0; j < 9; ++j) o9[j] = D[j];
    }
}

extern "C" void kernel_launch(void* const* d_in, const int* in_sizes, int n_in,
                              void* d_out, int out_size, void* d_ws, size_t ws_size,
                              hipStream_t stream) {
    const float* code = (const float*)d_in[0];
    const float* pos  = (const float*)d_in[1];
    const float* t1   = (const float*)d_in[2];
    const float* t2   = (const float*)d_in[3];
    const float* W1   = (const float*)d_in[4];
    const float* b1   = (const float*)d_in[5];
    const float* W2   = (const float*)d_in[6];
    const float* b2   = (const float*)d_in[7];
    const float* W3   = (const float*)d_in[8];
    const float* b3   = (const float*)d_in[9];
    float* out = (float*)d_out;
    const int N = in_sizes[1] / 3;           // 131072
    const int blocks = N / PPB;              // 2048
    velwarp<<<blocks, 256, 0, stream>>>(code, pos, t1, t2, W1, b1, W2, b2, W3, b3, out, N);
}